// Round 4
// baseline (568.158 us; speedup 1.0000x reference)
//
#include <hip/hip_runtime.h>

#define NLEVELS 16
#define LOG2T 19
#define TMASK ((1u << LOG2T) - 1u)
#define PRIME1 2654435761u

typedef float vf2 __attribute__((ext_vector_type(2)));
typedef float vf4 __attribute__((ext_vector_type(4)));

// One thread per (point b, level l), tid = b*16 + l (coalesced float2 stores).
// Gather-merge trick: PRIME0 == 1, so idx = (i0 ^ h) & mask. For even i0,
// the x-neighbor corner has idx10 = idx00 ^ 1 -> both corners of a row live
// in one aligned 16 B float4 -> 2 loads/point instead of 4. Odd i0 keeps 4
// float2 gathers. Expected lane-request count drops 25% (the R0/R1 evidence
// says we're bound by divergent-request throughput, ~0.2 req/cycle/CU).
__global__ __launch_bounds__(256) void hashgrid2d_merged(
    const float* __restrict__ x,
    const float* __restrict__ tables,
    float* __restrict__ out,
    int B)
{
    int tid = blockIdx.x * blockDim.x + threadIdx.x;
    int b = tid >> 4;
    if (b >= B) return;
    int l = tid & 15;

    // 16 consecutive lanes share b -> coalescer merges to one request + bcast
    vf2 xy = __builtin_nontemporal_load(reinterpret_cast<const vf2*>(x) + b);

    float res = (float)(256 << l);          // exact power of two
    float xs0 = xy.x * res;                 // exact (pow2 scale)
    float xs1 = xy.y * res;
    float v0 = floorf(xs0), v1 = floorf(xs1);
    float w0 = xs0 - v0,    w1 = xs1 - v1;

    unsigned i0 = (unsigned)(int)v0;
    unsigned i1 = (unsigned)(int)v1;
    unsigned hy0 = i1 * PRIME1;
    unsigned hy1 = hy0 + PRIME1;            // (i1+1)*PRIME1

    const vf2* tbl2 = reinterpret_cast<const vf2*>(tables) + ((size_t)l << LOG2T);
    const vf4* tbl4 = reinterpret_cast<const vf4*>(tbl2);

    float omw0 = 1.0f - w0;
    float c0x, c0y, c1x, c1y;               // rows lerped along x

    if ((i0 & 1u) == 0u) {
        // even i0: corners (i0, i0+1) of each row share an aligned float4
        unsigned iA0 = (i0 ^ hy0) & TMASK;  // row y   : corner i0 at iA0, corner i0+1 at iA0^1
        unsigned iA1 = (i0 ^ hy1) & TMASK;  // row y+1
        vf4 p0 = tbl4[iA0 >> 1];            // entries {2j, 2j+1}
        vf4 p1 = tbl4[iA1 >> 1];

        bool s0 = (iA0 & 1u) != 0u;         // corner i0 in high half?
        float e00x = s0 ? p0.z : p0.x, e00y = s0 ? p0.w : p0.y;
        float e10x = s0 ? p0.x : p0.z, e10y = s0 ? p0.y : p0.w;
        c0x = e00x * omw0 + e10x * w0;
        c0y = e00y * omw0 + e10y * w0;

        bool s1 = (iA1 & 1u) != 0u;
        float e01x = s1 ? p1.z : p1.x, e01y = s1 ? p1.w : p1.y;
        float e11x = s1 ? p1.x : p1.z, e11y = s1 ? p1.y : p1.w;
        c1x = e01x * omw0 + e11x * w0;
        c1y = e01y * omw0 + e11y * w0;
    } else {
        unsigned idx00 = ( i0        ^ hy0) & TMASK;
        unsigned idx01 = ( i0        ^ hy1) & TMASK;
        unsigned idx10 = ((i0 + 1u)  ^ hy0) & TMASK;
        unsigned idx11 = ((i0 + 1u)  ^ hy1) & TMASK;
        vf2 e00 = tbl2[idx00];
        vf2 e01 = tbl2[idx01];
        vf2 e10 = tbl2[idx10];
        vf2 e11 = tbl2[idx11];
        c0x = e00.x * omw0 + e10.x * w0;
        c0y = e00.y * omw0 + e10.y * w0;
        c1x = e01.x * omw0 + e11.x * w0;
        c1y = e01.y * omw0 + e11.y * w0;
    }

    float omw1 = 1.0f - w1;
    vf2 o;
    o.x = c0x * omw1 + c1x * w1;
    o.y = c0y * omw1 + c1y * w1;
    __builtin_nontemporal_store(o, reinterpret_cast<vf2*>(out) + tid);
}

extern "C" void kernel_launch(void* const* d_in, const int* in_sizes, int n_in,
                              void* d_out, int out_size, void* d_ws, size_t ws_size,
                              hipStream_t stream) {
    const float* x      = (const float*)d_in[0];
    const float* tables = (const float*)d_in[1];
    float* out          = (float*)d_out;
    int B = in_sizes[0] / 2;                 // x is (B, 2)

    int total = B * NLEVELS;
    int block = 256;
    int grid  = (total + block - 1) / block;
    hashgrid2d_merged<<<grid, block, 0, stream>>>(x, tables, out, B);
}

// Round 5
// 487.441 us; speedup vs baseline: 1.1656x; 1.1656x over previous
//
#include <hip/hip_runtime.h>
#include <hip/hip_fp16.h>

#define NLEVELS 16
#define LOG2T 19
#define TENTRIES (1u << LOG2T)
#define TMASK (TENTRIES - 1u)
#define PRIME1 2654435761u

typedef float vf2 __attribute__((ext_vector_type(2)));
typedef float vf4 __attribute__((ext_vector_type(4)));

// ---- prepass: f32 table (L*T entries x 2 floats) -> half2-per-entry in ws ----
// One thread converts 2 entries (16 B read, 8 B write), fully coalesced.
__global__ __launch_bounds__(256) void cvt_fp16_kernel(
    const vf4* __restrict__ src, uint2* __restrict__ dst, int npair)
{
    int i = blockIdx.x * blockDim.x + threadIdx.x;
    if (i >= npair) return;
    vf4 v = src[i];
    __half2 a = __floats2half2_rn(v.x, v.y);
    __half2 b = __floats2half2_rn(v.z, v.w);
    uint2 o;
    o.x = *reinterpret_cast<unsigned*>(&a);
    o.y = *reinterpret_cast<unsigned*>(&b);
    dst[i] = o;
}

// ---- main: one thread per (point, level); gathers 4 x 4 B half2 corners ----
// Divergent-gather bytes halved vs f32 path: 16 B/point-level instead of 32 B.
// R0/R1/R2 established time ~ divergent bytes (hit level & request count
// were shown irrelevant), so this predicts ~2x on the gather-bound part.
__global__ __launch_bounds__(256) void hashgrid2d_fp16(
    const float* __restrict__ x,
    const __half2* __restrict__ aux,
    float* __restrict__ out,
    int B)
{
    int tid = blockIdx.x * blockDim.x + threadIdx.x;
    int b = tid >> 4;
    if (b >= B) return;
    int l = tid & 15;

    vf2 xy = __builtin_nontemporal_load(reinterpret_cast<const vf2*>(x) + b);

    float res = (float)(256 << l);          // exact power of two
    float xs0 = xy.x * res;
    float xs1 = xy.y * res;
    float v0 = floorf(xs0), v1 = floorf(xs1);
    float w0 = xs0 - v0,    w1 = xs1 - v1;

    unsigned i0 = (unsigned)(int)v0;
    unsigned i1 = (unsigned)(int)v1;
    unsigned hy0 = i1 * PRIME1;
    unsigned hy1 = hy0 + PRIME1;            // (i1+1)*PRIME1

    unsigned idx00 = ( i0        ^ hy0) & TMASK;
    unsigned idx01 = ( i0        ^ hy1) & TMASK;
    unsigned idx10 = ((i0 + 1u)  ^ hy0) & TMASK;
    unsigned idx11 = ((i0 + 1u)  ^ hy1) & TMASK;

    const __half2* tbl = aux + ((size_t)l << LOG2T);
    __half2 e00 = tbl[idx00];
    __half2 e01 = tbl[idx01];
    __half2 e10 = tbl[idx10];
    __half2 e11 = tbl[idx11];

    float omw0 = 1.0f - w0, omw1 = 1.0f - w1;
    float c0x = __low2float(e00)  * omw0 + __low2float(e10)  * w0;
    float c0y = __high2float(e00) * omw0 + __high2float(e10) * w0;
    float c1x = __low2float(e01)  * omw0 + __low2float(e11)  * w0;
    float c1y = __high2float(e01) * omw0 + __high2float(e11) * w0;

    vf2 o;
    o.x = c0x * omw1 + c1x * w1;
    o.y = c0y * omw1 + c1y * w1;
    __builtin_nontemporal_store(o, reinterpret_cast<vf2*>(out) + tid);
}

// ---- f32 fallback (identical to R0) if ws is too small for the aux table ----
__global__ __launch_bounds__(256) void hashgrid2d_f32(
    const float* __restrict__ x,
    const float* __restrict__ tables,
    float* __restrict__ out,
    int B)
{
    int tid = blockIdx.x * blockDim.x + threadIdx.x;
    int b = tid >> 4;
    if (b >= B) return;
    int l = tid & 15;

    vf2 xy = __builtin_nontemporal_load(reinterpret_cast<const vf2*>(x) + b);
    float res = (float)(256 << l);
    float xs0 = xy.x * res, xs1 = xy.y * res;
    float v0 = floorf(xs0), v1 = floorf(xs1);
    float w0 = xs0 - v0,    w1 = xs1 - v1;
    unsigned i0 = (unsigned)(int)v0, i1 = (unsigned)(int)v1;
    unsigned hy0 = i1 * PRIME1, hy1 = hy0 + PRIME1;
    unsigned idx00 = ( i0       ^ hy0) & TMASK;
    unsigned idx01 = ( i0       ^ hy1) & TMASK;
    unsigned idx10 = ((i0 + 1u) ^ hy0) & TMASK;
    unsigned idx11 = ((i0 + 1u) ^ hy1) & TMASK;
    const vf2* tbl = reinterpret_cast<const vf2*>(tables) + ((size_t)l << LOG2T);
    vf2 e00 = tbl[idx00], e01 = tbl[idx01], e10 = tbl[idx10], e11 = tbl[idx11];
    float omw0 = 1.0f - w0, omw1 = 1.0f - w1;
    float c0x = e00.x * omw0 + e10.x * w0;
    float c0y = e00.y * omw0 + e10.y * w0;
    float c1x = e01.x * omw0 + e11.x * w0;
    float c1y = e01.y * omw0 + e11.y * w0;
    vf2 o;
    o.x = c0x * omw1 + c1x * w1;
    o.y = c0y * omw1 + c1y * w1;
    __builtin_nontemporal_store(o, reinterpret_cast<vf2*>(out) + tid);
}

extern "C" void kernel_launch(void* const* d_in, const int* in_sizes, int n_in,
                              void* d_out, int out_size, void* d_ws, size_t ws_size,
                              hipStream_t stream) {
    const float* x      = (const float*)d_in[0];
    const float* tables = (const float*)d_in[1];
    float* out          = (float*)d_out;
    int B = in_sizes[0] / 2;

    const size_t auxBytes = (size_t)NLEVELS * TENTRIES * 4;   // 32 MiB half2 table

    int total = B * NLEVELS;
    int block = 256;
    int grid  = (total + block - 1) / block;

    if (ws_size >= auxBytes) {
        // prepass: convert table to fp16 pairs in ws (deterministic every call)
        int npair = NLEVELS * TENTRIES / 2;        // 2 entries per thread
        int cgrid = (npair + block - 1) / block;
        cvt_fp16_kernel<<<cgrid, block, 0, stream>>>(
            reinterpret_cast<const vf4*>(tables),
            reinterpret_cast<uint2*>(d_ws), npair);
        hashgrid2d_fp16<<<grid, block, 0, stream>>>(
            x, reinterpret_cast<const __half2*>(d_ws), out, B);
    } else {
        hashgrid2d_f32<<<grid, block, 0, stream>>>(x, tables, out, B);
    }
}

// Round 6
// 243.986 us; speedup vs baseline: 2.3287x; 1.9978x over previous
//
#include <hip/hip_runtime.h>
#include <hip/hip_fp16.h>

#define NLEVELS 16
#define LOG2T 19
#define TENTRIES (1u << LOG2T)
#define TMASK (TENTRIES - 1u)
#define PRIME1 2654435761u
#define THREADS 256
#define PTS_PER_THREAD 4
#define PTS_PER_BLOCK (THREADS * PTS_PER_THREAD)

typedef float vf2 __attribute__((ext_vector_type(2)));
typedef float vf4 __attribute__((ext_vector_type(4)));

// ---- prepass: f32 table -> half2-per-entry table in ws (coalesced) ----
__global__ __launch_bounds__(256) void cvt_fp16_kernel(
    const vf4* __restrict__ src, uint2* __restrict__ dst, int npair)
{
    int i = blockIdx.x * blockDim.x + threadIdx.x;
    if (i >= npair) return;
    vf4 v = src[i];
    __half2 a = __floats2half2_rn(v.x, v.y);
    __half2 b = __floats2half2_rn(v.z, v.w);
    uint2 o;
    o.x = *reinterpret_cast<unsigned*>(&a);
    o.y = *reinterpret_cast<unsigned*>(&b);
    dst[i] = o;
}

// ---- main: level-partitioned (R1-proven L2 residency: FETCH 1.9GB->0.28GB),
// fp16 gathers (R3-proven -15%), and COALESCED level-major stores to ws.
// xcd = bid&7 owns levels {2*xcd, 2*xcd+1}, time-sliced, so each XCD's L2
// holds one 2MB fp16 table at a time. Streams (x, outT) are non-temporal so
// they don't evict the table.
__global__ __launch_bounds__(THREADS) void hashgrid2d_lvl_fp16(
    const float* __restrict__ x,
    const __half2* __restrict__ aux,
    vf2* __restrict__ outT,          // [NLEVELS][B] float2, in ws
    int B, int chunksPerLevel)
{
    int bid  = blockIdx.x;
    int xcd  = bid & 7;
    int seq  = bid >> 3;
    int half = (seq >= chunksPerLevel) ? 1 : 0;
    int level = 2 * xcd + half;
    int chunk = seq - half * chunksPerLevel;

    const __half2* __restrict__ tbl = aux + ((size_t)level << LOG2T);
    const vf2* __restrict__ x2 = reinterpret_cast<const vf2*>(x);
    float res = (float)(256 << level);      // exact power of two

    int base = chunk * PTS_PER_BLOCK + (int)threadIdx.x;

    __half2 e00[PTS_PER_THREAD], e01[PTS_PER_THREAD], e10[PTS_PER_THREAD], e11[PTS_PER_THREAD];
    float w0[PTS_PER_THREAD], w1[PTS_PER_THREAD];
    int   bidx[PTS_PER_THREAD];

    #pragma unroll
    for (int k = 0; k < PTS_PER_THREAD; ++k) {
        int b = base + k * THREADS;
        bidx[k] = b;
        if (b >= B) b = B - 1;              // clamp; store discarded below
        vf2 xy = __builtin_nontemporal_load(&x2[b]);

        float xs0 = xy.x * res;             // exact (pow2 scale)
        float xs1 = xy.y * res;
        float v0 = floorf(xs0), v1 = floorf(xs1);
        w0[k] = xs0 - v0;
        w1[k] = xs1 - v1;

        unsigned i0 = (unsigned)(int)v0;
        unsigned i1 = (unsigned)(int)v1;
        unsigned hy0 = i1 * PRIME1;
        unsigned hy1 = hy0 + PRIME1;        // (i1+1)*PRIME1

        unsigned idx00 = ( i0       ^ hy0) & TMASK;
        unsigned idx01 = ( i0       ^ hy1) & TMASK;
        unsigned idx10 = ((i0 + 1u) ^ hy0) & TMASK;
        unsigned idx11 = ((i0 + 1u) ^ hy1) & TMASK;

        e00[k] = tbl[idx00];
        e01[k] = tbl[idx01];
        e10[k] = tbl[idx10];
        e11[k] = tbl[idx11];
    }

    #pragma unroll
    for (int k = 0; k < PTS_PER_THREAD; ++k) {
        int b = bidx[k];
        if (b >= B) continue;
        float omw0 = 1.0f - w0[k], omw1 = 1.0f - w1[k];
        float c0x = __low2float(e00[k])  * omw0 + __low2float(e10[k])  * w0[k];
        float c0y = __high2float(e00[k]) * omw0 + __high2float(e10[k]) * w0[k];
        float c1x = __low2float(e01[k])  * omw0 + __low2float(e11[k])  * w0[k];
        float c1y = __high2float(e01[k]) * omw0 + __high2float(e11[k]) * w0[k];
        vf2 o;
        o.x = c0x * omw1 + c1x * w1[k];
        o.y = c0y * omw1 + c1y * w1[k];
        // level-major: consecutive threads -> consecutive b -> coalesced 8B
        __builtin_nontemporal_store(o, &outT[(size_t)level * B + b]);
    }
}

// ---- transpose pass: outT[l][b] -> out[b][l], LDS-tiled, both sides coalesced
__global__ __launch_bounds__(THREADS) void transpose_out(
    const vf2* __restrict__ outT, vf2* __restrict__ out, int B)
{
    __shared__ vf2 tile[NLEVELS][THREADS + 1];   // +1 pad: breaks bank alias
    int base = blockIdx.x * THREADS;
    int t = (int)threadIdx.x;

    #pragma unroll
    for (int l = 0; l < NLEVELS; ++l) {
        int b = base + t;
        if (b < B) tile[l][t] = __builtin_nontemporal_load(&outT[(size_t)l * B + b]);
    }
    __syncthreads();

    int l   = t & 15;
    int sub = t >> 4;
    #pragma unroll
    for (int g = 0; g < NLEVELS; ++g) {
        int i = g * 16 + sub;                    // point within tile
        int b = base + i;
        if (b < B)
            __builtin_nontemporal_store(tile[l][i], &out[(size_t)b * NLEVELS + l]);
    }
}

// ---- fallback A (R3, proven 487us): fp16 direct scattered-by-level stores ----
__global__ __launch_bounds__(256) void hashgrid2d_fp16(
    const float* __restrict__ x, const __half2* __restrict__ aux,
    float* __restrict__ out, int B)
{
    int tid = blockIdx.x * blockDim.x + threadIdx.x;
    int b = tid >> 4;
    if (b >= B) return;
    int l = tid & 15;
    vf2 xy = __builtin_nontemporal_load(reinterpret_cast<const vf2*>(x) + b);
    float res = (float)(256 << l);
    float xs0 = xy.x * res, xs1 = xy.y * res;
    float v0 = floorf(xs0), v1 = floorf(xs1);
    float w0 = xs0 - v0,    w1 = xs1 - v1;
    unsigned i0 = (unsigned)(int)v0, i1 = (unsigned)(int)v1;
    unsigned hy0 = i1 * PRIME1, hy1 = hy0 + PRIME1;
    unsigned idx00 = ( i0       ^ hy0) & TMASK;
    unsigned idx01 = ( i0       ^ hy1) & TMASK;
    unsigned idx10 = ((i0 + 1u) ^ hy0) & TMASK;
    unsigned idx11 = ((i0 + 1u) ^ hy1) & TMASK;
    const __half2* tbl = aux + ((size_t)l << LOG2T);
    __half2 e00 = tbl[idx00], e01 = tbl[idx01], e10 = tbl[idx10], e11 = tbl[idx11];
    float omw0 = 1.0f - w0, omw1 = 1.0f - w1;
    float c0x = __low2float(e00)  * omw0 + __low2float(e10)  * w0;
    float c0y = __high2float(e00) * omw0 + __high2float(e10) * w0;
    float c1x = __low2float(e01)  * omw0 + __low2float(e11)  * w0;
    float c1y = __high2float(e01) * omw0 + __high2float(e11) * w0;
    vf2 o;
    o.x = c0x * omw1 + c1x * w1;
    o.y = c0y * omw1 + c1y * w1;
    __builtin_nontemporal_store(o, reinterpret_cast<vf2*>(out) + tid);
}

// ---- fallback B (R0): pure f32, no workspace needed ----
__global__ __launch_bounds__(256) void hashgrid2d_f32(
    const float* __restrict__ x, const float* __restrict__ tables,
    float* __restrict__ out, int B)
{
    int tid = blockIdx.x * blockDim.x + threadIdx.x;
    int b = tid >> 4;
    if (b >= B) return;
    int l = tid & 15;
    vf2 xy = __builtin_nontemporal_load(reinterpret_cast<const vf2*>(x) + b);
    float res = (float)(256 << l);
    float xs0 = xy.x * res, xs1 = xy.y * res;
    float v0 = floorf(xs0), v1 = floorf(xs1);
    float w0 = xs0 - v0,    w1 = xs1 - v1;
    unsigned i0 = (unsigned)(int)v0, i1 = (unsigned)(int)v1;
    unsigned hy0 = i1 * PRIME1, hy1 = hy0 + PRIME1;
    unsigned idx00 = ( i0       ^ hy0) & TMASK;
    unsigned idx01 = ( i0       ^ hy1) & TMASK;
    unsigned idx10 = ((i0 + 1u) ^ hy0) & TMASK;
    unsigned idx11 = ((i0 + 1u) ^ hy1) & TMASK;
    const vf2* tbl = reinterpret_cast<const vf2*>(tables) + ((size_t)l << LOG2T);
    vf2 e00 = tbl[idx00], e01 = tbl[idx01], e10 = tbl[idx10], e11 = tbl[idx11];
    float omw0 = 1.0f - w0, omw1 = 1.0f - w1;
    float c0x = e00.x * omw0 + e10.x * w0;
    float c0y = e00.y * omw0 + e10.y * w0;
    float c1x = e01.x * omw0 + e11.x * w0;
    float c1y = e01.y * omw0 + e11.y * w0;
    vf2 o;
    o.x = c0x * omw1 + c1x * w1;
    o.y = c0y * omw1 + c1y * w1;
    __builtin_nontemporal_store(o, reinterpret_cast<vf2*>(out) + tid);
}

extern "C" void kernel_launch(void* const* d_in, const int* in_sizes, int n_in,
                              void* d_out, int out_size, void* d_ws, size_t ws_size,
                              hipStream_t stream) {
    const float* x      = (const float*)d_in[0];
    const float* tables = (const float*)d_in[1];
    float* out          = (float*)d_out;
    int B = in_sizes[0] / 2;

    const size_t auxBytes  = (size_t)NLEVELS * TENTRIES * 4;      // 32 MiB fp16 table
    const size_t outTBytes = (size_t)B * NLEVELS * sizeof(vf2);   // 128 MB staging

    int block = 256;
    int npair = NLEVELS * TENTRIES / 2;
    int cgrid = (npair + block - 1) / block;

    if (ws_size >= auxBytes + outTBytes) {
        __half2* aux = reinterpret_cast<__half2*>(d_ws);
        vf2* outT = reinterpret_cast<vf2*>((char*)d_ws + auxBytes);
        cvt_fp16_kernel<<<cgrid, block, 0, stream>>>(
            reinterpret_cast<const vf4*>(tables), reinterpret_cast<uint2*>(aux), npair);
        int chunksPerLevel = (B + PTS_PER_BLOCK - 1) / PTS_PER_BLOCK;
        int mgrid = NLEVELS * chunksPerLevel;
        hashgrid2d_lvl_fp16<<<mgrid, THREADS, 0, stream>>>(x, aux, outT, B, chunksPerLevel);
        int tgrid = (B + THREADS - 1) / THREADS;
        transpose_out<<<tgrid, THREADS, 0, stream>>>(outT, reinterpret_cast<vf2*>(out), B);
    } else if (ws_size >= auxBytes) {
        __half2* aux = reinterpret_cast<__half2*>(d_ws);
        cvt_fp16_kernel<<<cgrid, block, 0, stream>>>(
            reinterpret_cast<const vf4*>(tables), reinterpret_cast<uint2*>(aux), npair);
        int total = B * NLEVELS;
        int grid  = (total + block - 1) / block;
        hashgrid2d_fp16<<<grid, block, 0, stream>>>(x, aux, out, B);
    } else {
        int total = B * NLEVELS;
        int grid  = (total + block - 1) / block;
        hashgrid2d_f32<<<grid, block, 0, stream>>>(x, tables, out, B);
    }
}